// Round 1
// baseline (833.950 us; speedup 1.0000x reference)
//
#include <hip/hip_runtime.h>

typedef __attribute__((ext_vector_type(8))) __bf16 bf16x8;
typedef __attribute__((ext_vector_type(4))) float f32x4;

__device__ __forceinline__ unsigned short f2bf(float x) {
  union { float f; unsigned int u; } v; v.f = x;
  unsigned int r = v.u + 0x7fffu + ((v.u >> 16) & 1u);
  return (unsigned short)(r >> 16);
}
__device__ __forceinline__ float bf2f(unsigned short x) {
  union { unsigned int u; float f; } v; v.u = ((unsigned int)x) << 16;
  return v.f;
}
__device__ __forceinline__ void g2l16(const void* g, void* l) {
  __builtin_amdgcn_global_load_lds((const __attribute__((address_space(1))) void*)g,
                                   (__attribute__((address_space(3))) void*)l, 16, 0, 0);
}

// ---------------- fp32 -> bf16 convert (4 elems/thread) ----------------
__global__ __launch_bounds__(256) void cvt_f32_bf16_k(const float* __restrict__ in,
                                                      unsigned short* __restrict__ out) {
  int i = blockIdx.x * 256 + threadIdx.x;
  float4 v = ((const float4*)in)[i];
  ushort4 o;
  o.x = f2bf(v.x); o.y = f2bf(v.y); o.z = f2bf(v.z); o.w = f2bf(v.w);
  ((ushort4*)out)[i] = o;
}

// ------------- fp32 [R][C] -> bf16 [C][R] transpose+convert -------------
__global__ __launch_bounds__(256) void tr_cvt_k(const float* __restrict__ in,
                                                unsigned short* __restrict__ out,
                                                int R, int C) {
  __shared__ unsigned short t[64][65];
  int c0 = blockIdx.x * 64, r0 = blockIdx.y * 64;
  int tx = threadIdx.x & 63, tg = threadIdx.x >> 6;
#pragma unroll
  for (int i = 0; i < 16; i++) {
    int r = i * 4 + tg;
    t[r][tx] = f2bf(in[(size_t)(r0 + r) * C + c0 + tx]);
  }
  __syncthreads();
#pragma unroll
  for (int i = 0; i < 16; i++) {
    int c = i * 4 + tg;
    out[(size_t)(c0 + c) * R + r0 + tx] = t[tx][c];
  }
}

// ------------- bf16 [z][R][C] -> bf16 [z][C][R] transpose -------------
__global__ __launch_bounds__(256) void tr_b16_k(const unsigned short* __restrict__ in,
                                                unsigned short* __restrict__ out,
                                                int R, int C) {
  __shared__ unsigned short t[64][65];
  const size_t zoff = (size_t)blockIdx.z * R * C;
  int c0 = blockIdx.x * 64, r0 = blockIdx.y * 64;
  int tx = threadIdx.x & 63, tg = threadIdx.x >> 6;
#pragma unroll
  for (int i = 0; i < 16; i++) {
    int r = i * 4 + tg;
    t[r][tx] = in[zoff + (size_t)(r0 + r) * C + c0 + tx];
  }
  __syncthreads();
#pragma unroll
  for (int i = 0; i < 16; i++) {
    int c = i * 4 + tg;
    out[zoff + (size_t)(c0 + c) * R + r0 + tx] = t[tx][c];
  }
}

// ---------------- GEMM: C[M,N] = A[M,K](bf16) @ BT[N,K](bf16)^T ----------------
// 128x128 tile, BK=32, global_load_lds staging (m97 structure).
// EPI=0: scatter bf16 into q/k/v [B,H,S,D] buffers.  EPI=1: plain fp32 store.
template <int EPI>
__global__ __launch_bounds__(256) void gemm_bt_k(const unsigned short* __restrict__ A,
                                                 const unsigned short* __restrict__ BT,
                                                 int K, int N,
                                                 float* __restrict__ outF,
                                                 unsigned short* __restrict__ oq,
                                                 unsigned short* __restrict__ ok,
                                                 unsigned short* __restrict__ ov) {
  __shared__ __align__(16) unsigned short lA[128 * 32];
  __shared__ __align__(16) unsigned short lB[128 * 32];
  const int tid = threadIdx.x;
  const int w = tid >> 6, lane = tid & 63;
  const int quad = lane >> 4, l16 = lane & 15;
  const int m0 = blockIdx.y * 128, n0 = blockIdx.x * 128;
  const int wm = (w >> 1) * 64, wn = (w & 1) * 64;
  f32x4 acc[4][4] = {};
  const unsigned short* gA = A + (size_t)(m0 + w * 16 + (lane >> 2)) * K + (lane & 3) * 8;
  const unsigned short* gB = BT + (size_t)(n0 + w * 16 + (lane >> 2)) * K + (lane & 3) * 8;
  char* lAw = (char*)lA + w * 1024 + lane * 16;
  char* lBw = (char*)lB + w * 1024 + lane * 16;
  const size_t rowskip = (size_t)64 * K;
  for (int k0 = 0; k0 < K; k0 += 32) {
    g2l16(gA + k0, lAw);
    g2l16(gA + k0 + rowskip, lAw + 4096);
    g2l16(gB + k0, lBw);
    g2l16(gB + k0 + rowskip, lBw + 4096);
    __syncthreads();
    bf16x8 af[4], bfv[4];
#pragma unroll
    for (int i = 0; i < 4; i++)
      af[i] = *(const bf16x8*)((const char*)lA + (wm + i * 16 + l16) * 64 + quad * 16);
#pragma unroll
    for (int j = 0; j < 4; j++)
      bfv[j] = *(const bf16x8*)((const char*)lB + (wn + j * 16 + l16) * 64 + quad * 16);
#pragma unroll
    for (int i = 0; i < 4; i++)
#pragma unroll
      for (int j = 0; j < 4; j++)
        acc[i][j] = __builtin_amdgcn_mfma_f32_16x16x32_bf16(af[i], bfv[j], acc[i][j], 0, 0, 0);
    __syncthreads();
  }
  if (EPI == 0) {
    const int which = n0 >> 11;          // 0=q 1=k 2=v
    const int h = (n0 >> 7) & 15;        // tile spans exactly one head
    unsigned short* dst = (which == 0) ? oq : (which == 1) ? ok : ov;
#pragma unroll
    for (int i = 0; i < 4; i++) {
#pragma unroll
      for (int r = 0; r < 4; r++) {
        int mm = m0 + wm + i * 16 + quad * 4 + r;
        int b = mm >> 11, s = mm & 2047;
        size_t rb = ((size_t)(b * 16 + h) * 2048 + s) * 128;
#pragma unroll
        for (int j = 0; j < 4; j++)
          dst[rb + wn + j * 16 + l16] = f2bf(acc[i][j][r]);
      }
    }
  } else {
#pragma unroll
    for (int i = 0; i < 4; i++)
#pragma unroll
      for (int r = 0; r < 4; r++) {
        size_t rowb = (size_t)(m0 + wm + i * 16 + quad * 4 + r) * N;
#pragma unroll
        for (int j = 0; j < 4; j++)
          outF[rowb + n0 + wn + j * 16 + l16] = acc[i][j][r];
      }
  }
}

// ---------------- RoPE in-place on [B*H, S, 128] bf16 (+optional scale) ----------------
__global__ __launch_bounds__(256) void rope_k(unsigned short* __restrict__ buf, float scale) {
  int i = blockIdx.x * 256 + threadIdx.x;   // over B*H*S*64 pairs
  int d = i & 63;
  int s = (i >> 6) & 2047;
  int bh = i >> 17;
  size_t base = ((size_t)bh * 2048 + s) * 128;
  float a = bf2f(buf[base + d]);
  float b = bf2f(buf[base + 64 + d]);
  // theta = s * 10000^(-d/64)
  double theta = (double)s * exp2(-(double)d * (13.287712379549449 / 64.0));
  double sn, cs;
  sincos(theta, &sn, &cs);
  float c = (float)cs, sf = (float)sn;
  buf[base + d] = f2bf((a * c - b * sf) * scale);
  buf[base + 64 + d] = f2bf((b * c + a * sf) * scale);
}

// ---------------- flash attention: 1 block = 4 waves, wave = 16 q rows ----------------
// q,k: [B*H, S, 128] bf16 (q pre-scaled).  vt: [B*H, 128, S] bf16.
// out: [B*S, H*128] bf16.
__global__ __launch_bounds__(256) void attn_k(const unsigned short* __restrict__ qb,
                                              const unsigned short* __restrict__ kb,
                                              const unsigned short* __restrict__ vt,
                                              unsigned short* __restrict__ ob) {
  __shared__ __align__(16) __bf16 pbuf[4][16 * 72];   // wave-private P tiles
  const int tid = threadIdx.x;
  const int w = tid >> 6, lane = tid & 63;
  const int quad = lane >> 4, l16 = lane & 15;
  const int qt = blockIdx.x, bh = blockIdx.y;
  const int bi = bh >> 4, h = bh & 15;
  const int q0 = qt * 64 + w * 16;   // this wave's q-row base
  const unsigned short* qp = qb + (size_t)bh * 2048 * 128;
  const unsigned short* kp = kb + (size_t)bh * 2048 * 128;
  const unsigned short* vp = vt + (size_t)bh * 128 * 2048;
  __bf16* pw = pbuf[w];

  bf16x8 qf[4];
  {
    const unsigned short* qr = qp + (size_t)(q0 + l16) * 128 + quad * 8;
#pragma unroll
    for (int st = 0; st < 4; st++) qf[st] = *(const bf16x8*)(qr + st * 32);
  }
  float m_st[4] = {-1e30f, -1e30f, -1e30f, -1e30f};
  float l_st[4] = {0.f, 0.f, 0.f, 0.f};
  f32x4 o[8] = {};
  const int nkt = (q0 + 15) / 64 + 1;   // causal: only tiles touching/below diagonal
  for (int kt = 0; kt < nkt; kt++) {
    const int kt0 = kt * 64;
    // S-tile = Q Kt^T (pre-scaled): 16 q-rows x 64 k-cols
    f32x4 sc[4] = {};
#pragma unroll
    for (int ct = 0; ct < 4; ct++) {
      const unsigned short* kr = kp + (size_t)(kt0 + ct * 16 + l16) * 128 + quad * 8;
#pragma unroll
      for (int st = 0; st < 4; st++)
        sc[ct] = __builtin_amdgcn_mfma_f32_16x16x32_bf16(qf[st], *(const bf16x8*)(kr + st * 32),
                                                         sc[ct], 0, 0, 0);
    }
    // causal mask: only the diagonal (= last) tile can contain masked cols
    if (kt == nkt - 1) {
#pragma unroll
      for (int ct = 0; ct < 4; ct++) {
        int col = kt0 + ct * 16 + l16;
#pragma unroll
        for (int r = 0; r < 4; r++)
          if (col > q0 + quad * 4 + r) sc[ct][r] = -1e30f;
      }
    }
    // online softmax: row stats replicated across the 16 col-lanes
    float mx[4], sm[4], al[4];
#pragma unroll
    for (int r = 0; r < 4; r++)
      mx[r] = fmaxf(fmaxf(sc[0][r], sc[1][r]), fmaxf(sc[2][r], sc[3][r]));
#pragma unroll
    for (int m = 1; m < 16; m <<= 1)
#pragma unroll
      for (int r = 0; r < 4; r++)
        mx[r] = fmaxf(mx[r], __shfl_xor(mx[r], m, 64));
#pragma unroll
    for (int r = 0; r < 4; r++) {
      float mn = fmaxf(m_st[r], mx[r]);
      al[r] = __expf(m_st[r] - mn);
      m_st[r] = mn;
    }
#pragma unroll
    for (int ct = 0; ct < 4; ct++)
#pragma unroll
      for (int r = 0; r < 4; r++)
        sc[ct][r] = __expf(sc[ct][r] - m_st[r]);
#pragma unroll
    for (int r = 0; r < 4; r++)
      sm[r] = (sc[0][r] + sc[1][r]) + (sc[2][r] + sc[3][r]);
#pragma unroll
    for (int m = 1; m < 16; m <<= 1)
#pragma unroll
      for (int r = 0; r < 4; r++)
        sm[r] += __shfl_xor(sm[r], m, 64);
#pragma unroll
    for (int r = 0; r < 4; r++)
      l_st[r] = l_st[r] * al[r] + sm[r];
#pragma unroll
    for (int dt = 0; dt < 8; dt++)
#pragma unroll
      for (int r = 0; r < 4; r++)
        o[dt][r] *= al[r];
    // P: C-layout -> (LDS, bf16) -> A-layout
#pragma unroll
    for (int ct = 0; ct < 4; ct++)
#pragma unroll
      for (int r = 0; r < 4; r++)
        pw[(quad * 4 + r) * 72 + ct * 16 + l16] = (__bf16)sc[ct][r];
    bf16x8 pf0 = *(const bf16x8*)(pw + l16 * 72 + quad * 8);
    bf16x8 pf1 = *(const bf16x8*)(pw + l16 * 72 + 32 + quad * 8);
    // O += P @ V  (V^T rows are contiguous in s)
#pragma unroll
    for (int dt = 0; dt < 8; dt++) {
      const unsigned short* vr = vp + (size_t)(dt * 16 + l16) * 2048 + kt0 + quad * 8;
      o[dt] = __builtin_amdgcn_mfma_f32_16x16x32_bf16(pf0, *(const bf16x8*)(vr), o[dt], 0, 0, 0);
      o[dt] = __builtin_amdgcn_mfma_f32_16x16x32_bf16(pf1, *(const bf16x8*)(vr + 32), o[dt], 0, 0, 0);
    }
  }
  float inv[4];
#pragma unroll
  for (int r = 0; r < 4; r++) inv[r] = 1.0f / l_st[r];
#pragma unroll
  for (int dt = 0; dt < 8; dt++)
#pragma unroll
    for (int r = 0; r < 4; r++)
      ob[(size_t)(bi * 2048 + q0 + quad * 4 + r) * 2048 + h * 128 + dt * 16 + l16] =
          f2bf(o[dt][r] * inv[r]);
}

extern "C" void kernel_launch(void* const* d_in, const int* in_sizes, int n_in,
                              void* d_out, int out_size, void* d_ws, size_t ws_size,
                              hipStream_t stream) {
  const float* x = (const float*)d_in[0];
  const float* wqkv = (const float*)d_in[1];
  const float* wout = (const float*)d_in[2];
  // d_in[3] = mask, unused (causal analytically)
  char* ws = (char*)d_ws;
  const size_t MiB = 1ull << 20;
  unsigned short* xb    = (unsigned short*)(ws + 0);         // [4096,2048] bf16   16 MiB
  unsigned short* wqkvT = (unsigned short*)(ws + 16 * MiB);  // [6144,2048] bf16   24 MiB
  unsigned short* woutT = (unsigned short*)(ws + 40 * MiB);  // [2048,2048] bf16    8 MiB
  unsigned short* qb    = (unsigned short*)(ws + 48 * MiB);  // [32,2048,128] bf16 16 MiB
  unsigned short* kb    = (unsigned short*)(ws + 64 * MiB);  // [32,2048,128]      16 MiB
  unsigned short* vb    = (unsigned short*)(ws + 80 * MiB);  // [32,2048,128]      16 MiB
  unsigned short* vtb   = (unsigned short*)(ws + 96 * MiB);  // [32,128,2048]      16 MiB
  unsigned short* attnb = (unsigned short*)(ws + 112 * MiB); // [4096,2048] bf16   16 MiB
  float* outF = (float*)d_out;

  cvt_f32_bf16_k<<<8192, 256, 0, stream>>>(x, xb);
  tr_cvt_k<<<dim3(96, 32), 256, 0, stream>>>(wqkv, wqkvT, 2048, 6144);
  tr_cvt_k<<<dim3(32, 32), 256, 0, stream>>>(wout, woutT, 2048, 2048);
  gemm_bt_k<0><<<dim3(48, 32), 256, 0, stream>>>(xb, wqkvT, 2048, 6144, nullptr, qb, kb, vb);
  rope_k<<<16384, 256, 0, stream>>>(qb, 0.08838834764831845f);  // q: rope + 1/sqrt(128)
  rope_k<<<16384, 256, 0, stream>>>(kb, 1.0f);                   // k: rope only
  tr_b16_k<<<dim3(2, 32, 32), 256, 0, stream>>>(vb, vtb, 2048, 128);
  attn_k<<<dim3(32, 32), 256, 0, stream>>>(qb, kb, vtb, attnb);
  gemm_bt_k<1><<<dim3(16, 32), 256, 0, stream>>>(attnb, woutT, 2048, 2048, outF,
                                                 nullptr, nullptr, nullptr);
}

// Round 3
// 446.981 us; speedup vs baseline: 1.8657x; 1.8657x over previous
//
#include <hip/hip_runtime.h>

typedef __attribute__((ext_vector_type(8))) __bf16 bf16x8;
typedef __attribute__((ext_vector_type(4))) float f32x4;

__device__ __forceinline__ unsigned short f2bf(float x) {
  union { float f; unsigned int u; } v; v.f = x;
  unsigned int r = v.u + 0x7fffu + ((v.u >> 16) & 1u);
  return (unsigned short)(r >> 16);
}
__device__ __forceinline__ float bf2f(unsigned short x) {
  union { unsigned int u; float f; } v; v.u = ((unsigned int)x) << 16;
  return v.f;
}
__device__ __forceinline__ void g2l16(const void* g, void* l) {
  __builtin_amdgcn_global_load_lds((const __attribute__((address_space(1))) void*)g,
                                   (__attribute__((address_space(3))) void*)l, 16, 0, 0);
}

// ---------------- fp32 -> bf16 convert (4 elems/thread) ----------------
__global__ __launch_bounds__(256) void cvt_f32_bf16_k(const float* __restrict__ in,
                                                      unsigned short* __restrict__ out) {
  int i = blockIdx.x * 256 + threadIdx.x;
  float4 v = ((const float4*)in)[i];
  ushort4 o;
  o.x = f2bf(v.x); o.y = f2bf(v.y); o.z = f2bf(v.z); o.w = f2bf(v.w);
  ((ushort4*)out)[i] = o;
}

// ------------- fp32 [R][C] -> bf16 [C][R] transpose+convert -------------
__global__ __launch_bounds__(256) void tr_cvt_k(const float* __restrict__ in,
                                                unsigned short* __restrict__ out,
                                                int R, int C) {
  __shared__ unsigned short t[64][65];
  int c0 = blockIdx.x * 64, r0 = blockIdx.y * 64;
  int tx = threadIdx.x & 63, tg = threadIdx.x >> 6;
#pragma unroll
  for (int i = 0; i < 16; i++) {
    int r = i * 4 + tg;
    t[r][tx] = f2bf(in[(size_t)(r0 + r) * C + c0 + tx]);
  }
  __syncthreads();
#pragma unroll
  for (int i = 0; i < 16; i++) {
    int c = i * 4 + tg;
    out[(size_t)(c0 + c) * R + r0 + tx] = t[tx][c];
  }
}

// ------------- bf16 [z][R][C] -> bf16 [z][C][R] transpose -------------
__global__ __launch_bounds__(256) void tr_b16_k(const unsigned short* __restrict__ in,
                                                unsigned short* __restrict__ out,
                                                int R, int C) {
  __shared__ unsigned short t[64][65];
  const size_t zoff = (size_t)blockIdx.z * R * C;
  int c0 = blockIdx.x * 64, r0 = blockIdx.y * 64;
  int tx = threadIdx.x & 63, tg = threadIdx.x >> 6;
#pragma unroll
  for (int i = 0; i < 16; i++) {
    int r = i * 4 + tg;
    t[r][tx] = in[zoff + (size_t)(r0 + r) * C + c0 + tx];
  }
  __syncthreads();
#pragma unroll
  for (int i = 0; i < 16; i++) {
    int c = i * 4 + tg;
    out[zoff + (size_t)(c0 + c) * R + r0 + tx] = t[tx][c];
  }
}

// ---------------- GEMM: C[M,N] = A[M,K](bf16) @ BT[N,K](bf16)^T ----------------
// 128x128 tile, BK=32, global_load_lds staging (m97 structure).
// EPI=0: scatter bf16 into q/k/v [B,H,S,D] buffers.  EPI=1: plain fp32 store.
template <int EPI>
__global__ __launch_bounds__(256) void gemm_bt_k(const unsigned short* __restrict__ A,
                                                 const unsigned short* __restrict__ BT,
                                                 int K, int N,
                                                 float* __restrict__ outF,
                                                 unsigned short* __restrict__ oq,
                                                 unsigned short* __restrict__ ok,
                                                 unsigned short* __restrict__ ov) {
  __shared__ __align__(16) unsigned short lA[128 * 32];
  __shared__ __align__(16) unsigned short lB[128 * 32];
  const int tid = threadIdx.x;
  const int w = tid >> 6, lane = tid & 63;
  const int quad = lane >> 4, l16 = lane & 15;
  const int m0 = blockIdx.y * 128, n0 = blockIdx.x * 128;
  const int wm = (w >> 1) * 64, wn = (w & 1) * 64;
  f32x4 acc[4][4] = {};
  const unsigned short* gA = A + (size_t)(m0 + w * 16 + (lane >> 2)) * K + (lane & 3) * 8;
  const unsigned short* gB = BT + (size_t)(n0 + w * 16 + (lane >> 2)) * K + (lane & 3) * 8;
  char* lAw = (char*)lA + w * 1024 + lane * 16;
  char* lBw = (char*)lB + w * 1024 + lane * 16;
  const size_t rowskip = (size_t)64 * K;
  for (int k0 = 0; k0 < K; k0 += 32) {
    g2l16(gA + k0, lAw);
    g2l16(gA + k0 + rowskip, lAw + 4096);
    g2l16(gB + k0, lBw);
    g2l16(gB + k0 + rowskip, lBw + 4096);
    __syncthreads();
    bf16x8 af[4], bfv[4];
#pragma unroll
    for (int i = 0; i < 4; i++)
      af[i] = *(const bf16x8*)((const char*)lA + (wm + i * 16 + l16) * 64 + quad * 16);
#pragma unroll
    for (int j = 0; j < 4; j++)
      bfv[j] = *(const bf16x8*)((const char*)lB + (wn + j * 16 + l16) * 64 + quad * 16);
#pragma unroll
    for (int i = 0; i < 4; i++)
#pragma unroll
      for (int j = 0; j < 4; j++)
        acc[i][j] = __builtin_amdgcn_mfma_f32_16x16x32_bf16(af[i], bfv[j], acc[i][j], 0, 0, 0);
    __syncthreads();
  }
  if (EPI == 0) {
    const int which = n0 >> 11;          // 0=q 1=k 2=v
    const int h = (n0 >> 7) & 15;        // tile spans exactly one head
    unsigned short* dst = (which == 0) ? oq : (which == 1) ? ok : ov;
#pragma unroll
    for (int i = 0; i < 4; i++) {
#pragma unroll
      for (int r = 0; r < 4; r++) {
        int mm = m0 + wm + i * 16 + quad * 4 + r;
        int b = mm >> 11, s = mm & 2047;
        size_t rb = ((size_t)(b * 16 + h) * 2048 + s) * 128;
#pragma unroll
        for (int j = 0; j < 4; j++)
          dst[rb + wn + j * 16 + l16] = f2bf(acc[i][j][r]);
      }
    }
  } else {
#pragma unroll
    for (int i = 0; i < 4; i++)
#pragma unroll
      for (int r = 0; r < 4; r++) {
        size_t rowb = (size_t)(m0 + wm + i * 16 + quad * 4 + r) * N;
#pragma unroll
        for (int j = 0; j < 4; j++)
          outF[rowb + n0 + wn + j * 16 + l16] = acc[i][j][r];
      }
  }
}

// ---------------- RoPE in-place on [B*H, S, 128] bf16 (+optional scale) ----------------
__global__ __launch_bounds__(256) void rope_k(unsigned short* __restrict__ buf, float scale) {
  int i = blockIdx.x * 256 + threadIdx.x;   // over B*H*S*64 pairs
  int d = i & 63;
  int s = (i >> 6) & 2047;
  int bh = i >> 17;
  size_t base = ((size_t)bh * 2048 + s) * 128;
  float a = bf2f(buf[base + d]);
  float b = bf2f(buf[base + 64 + d]);
  // theta = s * 10000^(-d/64)
  double theta = (double)s * exp2(-(double)d * (13.287712379549449 / 64.0));
  double sn, cs;
  sincos(theta, &sn, &cs);
  float c = (float)cs, sf = (float)sn;
  buf[base + d] = f2bf((a * c - b * sf) * scale);
  buf[base + 64 + d] = f2bf((b * c + a * sf) * scale);
}

// ---------------- flash attention v2 ----------------
// Block = 128 q-rows (4 waves x 32 rows). K/V 64-wide tiles staged in LDS
// (XOR-swizzled 16B chunks: coalesced global_load_lds + conflict-free ds_read_b128).
// No-max softmax: unnormalized exp accumulation, single l-reduce at the end.
// q,k: [B*H, S, 128] bf16 (q pre-scaled by 1/sqrt(D)); vt: [B*H, 128, S] bf16.
// out: [B*S, H*128] bf16.
__global__ __launch_bounds__(256, 2) void attn_k(const unsigned short* __restrict__ qb,
                                                 const unsigned short* __restrict__ kb,
                                                 const unsigned short* __restrict__ vt,
                                                 unsigned short* __restrict__ ob) {
  __shared__ __align__(16) unsigned short lK[64 * 128];   // chunk l = row*16 + (cg^row&15)
  __shared__ __align__(16) unsigned short lV[128 * 64];   // chunk l = d*8 + (sg^d&7)
  __shared__ __align__(16) __bf16 pbuf[4][32 * 72];       // wave-private P (stride 72)
  const int tid = threadIdx.x;
  const int w = tid >> 6, lane = tid & 63;
  const int quad = lane >> 4, l16 = lane & 15;
  // complementary qt pairing for causal load balance
  const int qt = (blockIdx.y < 16) ? (int)blockIdx.x : 15 - (int)blockIdx.x;
  const int bh = blockIdx.y;
  const int bi = bh >> 4, h = bh & 15;
  const int q0w = qt * 128 + w * 32;
  const unsigned short* qp = qb + (size_t)bh * 2048 * 128;
  const unsigned short* kp = kb + (size_t)bh * 2048 * 128;
  const unsigned short* vp = vt + (size_t)bh * 128 * 2048;
  __bf16* pw = pbuf[w];

  // Q fragments: 2 row-groups x 4 k-chunks, A-layout
  bf16x8 qf[2][4];
#pragma unroll
  for (int rg = 0; rg < 2; rg++) {
    const unsigned short* qr = qp + (size_t)(q0w + rg * 16 + l16) * 128 + quad * 8;
#pragma unroll
    for (int st = 0; st < 4; st++) qf[rg][st] = *(const bf16x8*)(qr + st * 32);
  }
  f32x4 o[2][8] = {};
  f32x4 lsum[2] = {};

  // staging index precompute (chunk l = j*256 + tid)
  const int krow = tid >> 4;                       // + j*16
  const int kcg = (tid & 15) ^ krow;               // row&15 == krow (krow<16)
  const int vd = tid >> 3;                         // + j*32
  const int vsg = (tid & 7) ^ ((tid >> 3) & 7);
  unsigned short* lKdst = lK + (size_t)tid * 8;    // + j*2048 shorts
  unsigned short* lVdst = lV + (size_t)tid * 8;

  const int nkt = 2 * qt + 2;                      // block-uniform (barriers)
  const int myNkt = (q0w + 31) / 64 + 1;           // this wave's causal bound
  for (int kt = 0; kt < nkt; kt++) {
    const int kt0 = kt * 64;
#pragma unroll
    for (int j = 0; j < 4; j++) {
      g2l16(kp + (size_t)(kt0 + j * 16 + krow) * 128 + kcg * 8, lKdst + j * 2048);
      g2l16(vp + (size_t)(j * 32 + vd) * 2048 + kt0 + vsg * 8, lVdst + j * 2048);
    }
    __syncthreads();
    if (kt < myNkt) {
      // S = Q K^T (pre-scaled): 32 q-rows x 64 k-cols
      f32x4 sc[2][4] = {};
#pragma unroll
      for (int ct = 0; ct < 4; ct++) {
        const int nrow = ct * 16 + l16;
#pragma unroll
        for (int st = 0; st < 4; st++) {
          bf16x8 kf = *(const bf16x8*)(lK + ((size_t)nrow * 16 + ((st * 4 + quad) ^ l16)) * 8);
          sc[0][ct] = __builtin_amdgcn_mfma_f32_16x16x32_bf16(qf[0][st], kf, sc[0][ct], 0, 0, 0);
          sc[1][ct] = __builtin_amdgcn_mfma_f32_16x16x32_bf16(qf[1][st], kf, sc[1][ct], 0, 0, 0);
        }
      }
      // exp (no max-subtract), causal mask only on the wave's LAST tile
      // (structurally exact: last tile always straddles/touches the diagonal,
      //  second-to-last never does — verified for all 4 wave offsets)
      const bool needmask = (kt == myNkt - 1);
#pragma unroll
      for (int rg = 0; rg < 2; rg++)
#pragma unroll
        for (int ct = 0; ct < 4; ct++) {
          const int col = kt0 + ct * 16 + l16;
          const int rowb = q0w + rg * 16 + quad * 4;
#pragma unroll
          for (int r = 0; r < 4; r++) {
            float s = sc[rg][ct][r];
            if (needmask && col > rowb + r) s = -1e30f;
            float e = __expf(s);
            lsum[rg][r] += e;
            pw[(rg * 16 + quad * 4 + r) * 72 + ct * 16 + l16] = (__bf16)e;
          }
        }
      // P: C-layout -> LDS -> A-layout fragments
      bf16x8 pf[2][2];
#pragma unroll
      for (int rg = 0; rg < 2; rg++)
#pragma unroll
        for (int sb = 0; sb < 2; sb++)
          pf[rg][sb] = *(const bf16x8*)(pw + (rg * 16 + l16) * 72 + sb * 32 + quad * 8);
      // O += P @ V
#pragma unroll
      for (int dt = 0; dt < 8; dt++) {
#pragma unroll
        for (int sb = 0; sb < 2; sb++) {
          bf16x8 vf = *(const bf16x8*)(lV +
              ((size_t)(dt * 16 + l16) * 8 + ((sb * 4 + quad) ^ (l16 & 7))) * 8);
          o[0][dt] = __builtin_amdgcn_mfma_f32_16x16x32_bf16(pf[0][sb], vf, o[0][dt], 0, 0, 0);
          o[1][dt] = __builtin_amdgcn_mfma_f32_16x16x32_bf16(pf[1][sb], vf, o[1][dt], 0, 0, 0);
        }
      }
    }
    __syncthreads();
  }
  // reduce l across the 16 col-lanes (once per wave)
#pragma unroll
  for (int m = 1; m < 16; m <<= 1)
#pragma unroll
    for (int rg = 0; rg < 2; rg++)
#pragma unroll
      for (int r = 0; r < 4; r++)
        lsum[rg][r] += __shfl_xor(lsum[rg][r], m, 64);
  float inv[2][4];
#pragma unroll
  for (int rg = 0; rg < 2; rg++)
#pragma unroll
    for (int r = 0; r < 4; r++) inv[rg][r] = 1.0f / lsum[rg][r];
#pragma unroll
  for (int rg = 0; rg < 2; rg++)
#pragma unroll
    for (int dt = 0; dt < 8; dt++)
#pragma unroll
      for (int r = 0; r < 4; r++)
        ob[(size_t)(bi * 2048 + q0w + rg * 16 + quad * 4 + r) * 2048 + h * 128 + dt * 16 + l16] =
            f2bf(o[rg][dt][r] * inv[rg][r]);
}

extern "C" void kernel_launch(void* const* d_in, const int* in_sizes, int n_in,
                              void* d_out, int out_size, void* d_ws, size_t ws_size,
                              hipStream_t stream) {
  const float* x = (const float*)d_in[0];
  const float* wqkv = (const float*)d_in[1];
  const float* wout = (const float*)d_in[2];
  // d_in[3] = mask, unused (causal analytically)
  char* ws = (char*)d_ws;
  const size_t MiB = 1ull << 20;
  unsigned short* xb    = (unsigned short*)(ws + 0);         // [4096,2048] bf16   16 MiB
  unsigned short* wqkvT = (unsigned short*)(ws + 16 * MiB);  // [6144,2048] bf16   24 MiB
  unsigned short* woutT = (unsigned short*)(ws + 40 * MiB);  // [2048,2048] bf16    8 MiB
  unsigned short* qb    = (unsigned short*)(ws + 48 * MiB);  // [32,2048,128] bf16 16 MiB
  unsigned short* kb    = (unsigned short*)(ws + 64 * MiB);  // [32,2048,128]      16 MiB
  unsigned short* vb    = (unsigned short*)(ws + 80 * MiB);  // [32,2048,128]      16 MiB
  unsigned short* vtb   = (unsigned short*)(ws + 96 * MiB);  // [32,128,2048]      16 MiB
  unsigned short* attnb = (unsigned short*)(ws + 112 * MiB); // [4096,2048] bf16   16 MiB
  float* outF = (float*)d_out;

  cvt_f32_bf16_k<<<8192, 256, 0, stream>>>(x, xb);
  tr_cvt_k<<<dim3(96, 32), 256, 0, stream>>>(wqkv, wqkvT, 2048, 6144);
  tr_cvt_k<<<dim3(32, 32), 256, 0, stream>>>(wout, woutT, 2048, 2048);
  gemm_bt_k<0><<<dim3(48, 32), 256, 0, stream>>>(xb, wqkvT, 2048, 6144, nullptr, qb, kb, vb);
  rope_k<<<16384, 256, 0, stream>>>(qb, 0.08838834764831845f);  // q: rope + 1/sqrt(128)
  rope_k<<<16384, 256, 0, stream>>>(kb, 1.0f);                   // k: rope only
  tr_b16_k<<<dim3(2, 32, 32), 256, 0, stream>>>(vb, vtb, 2048, 128);
  attn_k<<<dim3(16, 32), 256, 0, stream>>>(qb, kb, vtb, attnb);
  gemm_bt_k<1><<<dim3(16, 32), 256, 0, stream>>>(attnb, woutT, 2048, 2048, outF,
                                                 nullptr, nullptr, nullptr);
}

// Round 4
// 400.526 us; speedup vs baseline: 2.0821x; 1.1160x over previous
//
#include <hip/hip_runtime.h>

typedef __attribute__((ext_vector_type(8))) __bf16 bf16x8;
typedef __attribute__((ext_vector_type(4))) float f32x4;

__device__ __forceinline__ unsigned short f2bf(float x) {
  union { float f; unsigned int u; } v; v.f = x;
  unsigned int r = v.u + 0x7fffu + ((v.u >> 16) & 1u);
  return (unsigned short)(r >> 16);
}
__device__ __forceinline__ float bf2f(unsigned short x) {
  union { unsigned int u; float f; } v; v.u = ((unsigned int)x) << 16;
  return v.f;
}
__device__ __forceinline__ void g2l16(const void* g, void* l) {
  __builtin_amdgcn_global_load_lds((const __attribute__((address_space(1))) void*)g,
                                   (__attribute__((address_space(3))) void*)l, 16, 0, 0);
}

// ---------------- fp32 -> bf16 convert (4 elems/thread) ----------------
__global__ __launch_bounds__(256) void cvt_f32_bf16_k(const float* __restrict__ in,
                                                      unsigned short* __restrict__ out) {
  int i = blockIdx.x * 256 + threadIdx.x;
  float4 v = ((const float4*)in)[i];
  ushort4 o;
  o.x = f2bf(v.x); o.y = f2bf(v.y); o.z = f2bf(v.z); o.w = f2bf(v.w);
  ((ushort4*)out)[i] = o;
}

// ------------- fp32 [R][C] -> bf16 [C][R] transpose+convert -------------
__global__ __launch_bounds__(256) void tr_cvt_k(const float* __restrict__ in,
                                                unsigned short* __restrict__ out,
                                                int R, int C) {
  __shared__ unsigned short t[64][65];
  int c0 = blockIdx.x * 64, r0 = blockIdx.y * 64;
  int tx = threadIdx.x & 63, tg = threadIdx.x >> 6;
#pragma unroll
  for (int i = 0; i < 16; i++) {
    int r = i * 4 + tg;
    t[r][tx] = f2bf(in[(size_t)(r0 + r) * C + c0 + tx]);
  }
  __syncthreads();
#pragma unroll
  for (int i = 0; i < 16; i++) {
    int c = i * 4 + tg;
    out[(size_t)(c0 + c) * R + r0 + tx] = t[tx][c];
  }
}

// ------------- bf16 [z][R][C] -> bf16 [z][C][R] transpose -------------
__global__ __launch_bounds__(256) void tr_b16_k(const unsigned short* __restrict__ in,
                                                unsigned short* __restrict__ out,
                                                int R, int C) {
  __shared__ unsigned short t[64][65];
  const size_t zoff = (size_t)blockIdx.z * R * C;
  int c0 = blockIdx.x * 64, r0 = blockIdx.y * 64;
  int tx = threadIdx.x & 63, tg = threadIdx.x >> 6;
#pragma unroll
  for (int i = 0; i < 16; i++) {
    int r = i * 4 + tg;
    t[r][tx] = in[zoff + (size_t)(r0 + r) * C + c0 + tx];
  }
  __syncthreads();
#pragma unroll
  for (int i = 0; i < 16; i++) {
    int c = i * 4 + tg;
    out[zoff + (size_t)(c0 + c) * R + r0 + tx] = t[tx][c];
  }
}

// ---------------- GEMM: C[M,N] = A[M,K](bf16) @ BT[N,K](bf16)^T ----------------
// 128x128 tile, BK=64, global_load_lds staging with XOR-swizzled chunk layout:
// physical chunk p of row r holds logical chunk p^(r&7)  ->  conflict-free
// ds_read_b128 fragment reads (start bank 4*((ks*4+quad)^(l16&7)) covers all
// 8 bank-groups x2 per quarter-wave).  Staging stays fully coalesced (chunks
// permute within each 128B row segment).
// EPI=0: scatter bf16 into q/k/v [B,H,S,D] buffers.  EPI=1: plain fp32 store.
template <int EPI>
__global__ __launch_bounds__(256) void gemm_bt_k(const unsigned short* __restrict__ A,
                                                 const unsigned short* __restrict__ BT,
                                                 int K, int N,
                                                 float* __restrict__ outF,
                                                 unsigned short* __restrict__ oq,
                                                 unsigned short* __restrict__ ok,
                                                 unsigned short* __restrict__ ov) {
  __shared__ __align__(16) unsigned short lA[128 * 64];   // 16 KiB
  __shared__ __align__(16) unsigned short lB[128 * 64];   // 16 KiB
  const int tid = threadIdx.x;
  const int w = tid >> 6, lane = tid & 63;
  const int quad = lane >> 4, l16 = lane & 15;
  const int m0 = blockIdx.y * 128, n0 = blockIdx.x * 128;
  const int wm = (w >> 1) * 64, wn = (w & 1) * 64;
  f32x4 acc[4][4] = {};
  const int srow = tid >> 3;                     // staging row 0..31 (+j*32)
  const int schunk = (tid & 7) ^ (srow & 7);     // swizzled logical chunk
  const unsigned short* gA = A + (size_t)(m0 + srow) * K + schunk * 8;
  const unsigned short* gB = BT + (size_t)(n0 + srow) * K + schunk * 8;
  char* ldA = (char*)lA + tid * 16;
  char* ldB = (char*)lB + tid * 16;
  const size_t rskip = (size_t)32 * K;
  for (int k0 = 0; k0 < K; k0 += 64) {
#pragma unroll
    for (int j = 0; j < 4; j++) {
      g2l16(gA + k0 + j * rskip, ldA + j * 4096);
      g2l16(gB + k0 + j * rskip, ldB + j * 4096);
    }
    __syncthreads();
#pragma unroll
    for (int ks = 0; ks < 2; ks++) {
      bf16x8 af[4], bfv[4];
#pragma unroll
      for (int i = 0; i < 4; i++)
        af[i] = *(const bf16x8*)((const char*)lA + (size_t)(wm + i * 16 + l16) * 128 +
                                 ((size_t)((ks * 4 + quad) ^ (l16 & 7)) * 16));
#pragma unroll
      for (int j = 0; j < 4; j++)
        bfv[j] = *(const bf16x8*)((const char*)lB + (size_t)(wn + j * 16 + l16) * 128 +
                                  ((size_t)((ks * 4 + quad) ^ (l16 & 7)) * 16));
#pragma unroll
      for (int i = 0; i < 4; i++)
#pragma unroll
        for (int j = 0; j < 4; j++)
          acc[i][j] = __builtin_amdgcn_mfma_f32_16x16x32_bf16(af[i], bfv[j], acc[i][j], 0, 0, 0);
    }
    __syncthreads();
  }
  if (EPI == 0) {
    const int which = n0 >> 11;          // 0=q 1=k 2=v
    const int h = (n0 >> 7) & 15;        // tile spans exactly one head
    unsigned short* dst = (which == 0) ? oq : (which == 1) ? ok : ov;
#pragma unroll
    for (int i = 0; i < 4; i++) {
#pragma unroll
      for (int r = 0; r < 4; r++) {
        int mm = m0 + wm + i * 16 + quad * 4 + r;
        int b = mm >> 11, s = mm & 2047;
        size_t rb = ((size_t)(b * 16 + h) * 2048 + s) * 128;
#pragma unroll
        for (int j = 0; j < 4; j++)
          dst[rb + wn + j * 16 + l16] = f2bf(acc[i][j][r]);
      }
    }
  } else {
#pragma unroll
    for (int i = 0; i < 4; i++)
#pragma unroll
      for (int r = 0; r < 4; r++) {
        size_t rowb = (size_t)(m0 + wm + i * 16 + quad * 4 + r) * N;
#pragma unroll
        for (int j = 0; j < 4; j++)
          outF[rowb + n0 + wn + j * 16 + l16] = acc[i][j][r];
      }
  }
}

// -------- RoPE in-place on q and k [B*H, S, 128] bf16 (q also scaled) --------
__global__ __launch_bounds__(256) void rope_k(unsigned short* __restrict__ q,
                                              unsigned short* __restrict__ k) {
  const int bid = blockIdx.x;
  unsigned short* buf = (bid < 16384) ? q : k;
  const float scale = (bid < 16384) ? 0.08838834764831845f : 1.0f;
  int i = (bid & 16383) * 256 + threadIdx.x;   // over B*H*S*64 pairs
  int d = i & 63;
  int s = (i >> 6) & 2047;
  int bh = i >> 17;
  size_t base = ((size_t)bh * 2048 + s) * 128;
  float a = bf2f(buf[base + d]);
  float b = bf2f(buf[base + 64 + d]);
  // theta = s * 10000^(-d/64);  fp32 phase error ~2e-4 rad << bf16 quantization
  float theta = (float)s * exp2f(-(float)d * (13.287712379549449f / 64.0f));
  float sn, cs;
  __sincosf(theta, &sn, &cs);
  buf[base + d] = f2bf((a * cs - b * sn) * scale);
  buf[base + 64 + d] = f2bf((b * cs + a * sn) * scale);
}

// ---------------- flash attention v2 ----------------
// Block = 128 q-rows (4 waves x 32 rows). K/V 64-wide tiles staged in LDS
// (XOR-swizzled 16B chunks: coalesced global_load_lds + conflict-free ds_read_b128).
// No-max softmax: unnormalized exp accumulation, single l-reduce at the end.
// q,k: [B*H, S, 128] bf16 (q pre-scaled by 1/sqrt(D)); vt: [B*H, 128, S] bf16.
// out: [B*S, H*128] bf16.
__global__ __launch_bounds__(256, 2) void attn_k(const unsigned short* __restrict__ qb,
                                                 const unsigned short* __restrict__ kb,
                                                 const unsigned short* __restrict__ vt,
                                                 unsigned short* __restrict__ ob) {
  __shared__ __align__(16) unsigned short lK[64 * 128];   // chunk l = row*16 + (cg^row&15)
  __shared__ __align__(16) unsigned short lV[128 * 64];   // chunk l = d*8 + (sg^d&7)
  __shared__ __align__(16) __bf16 pbuf[4][32 * 72];       // wave-private P (stride 72)
  const int tid = threadIdx.x;
  const int w = tid >> 6, lane = tid & 63;
  const int quad = lane >> 4, l16 = lane & 15;
  // complementary qt pairing for causal load balance
  const int qt = (blockIdx.y < 16) ? (int)blockIdx.x : 15 - (int)blockIdx.x;
  const int bh = blockIdx.y;
  const int bi = bh >> 4, h = bh & 15;
  const int q0w = qt * 128 + w * 32;
  const unsigned short* qp = qb + (size_t)bh * 2048 * 128;
  const unsigned short* kp = kb + (size_t)bh * 2048 * 128;
  const unsigned short* vp = vt + (size_t)bh * 128 * 2048;
  __bf16* pw = pbuf[w];

  // Q fragments: 2 row-groups x 4 k-chunks, A-layout
  bf16x8 qf[2][4];
#pragma unroll
  for (int rg = 0; rg < 2; rg++) {
    const unsigned short* qr = qp + (size_t)(q0w + rg * 16 + l16) * 128 + quad * 8;
#pragma unroll
    for (int st = 0; st < 4; st++) qf[rg][st] = *(const bf16x8*)(qr + st * 32);
  }
  f32x4 o[2][8] = {};
  f32x4 lsum[2] = {};

  // staging index precompute (chunk l = j*256 + tid)
  const int krow = tid >> 4;                       // + j*16
  const int kcg = (tid & 15) ^ krow;               // row&15 == krow (krow<16)
  const int vd = tid >> 3;                         // + j*32
  const int vsg = (tid & 7) ^ ((tid >> 3) & 7);
  unsigned short* lKdst = lK + (size_t)tid * 8;    // + j*2048 shorts
  unsigned short* lVdst = lV + (size_t)tid * 8;

  const int nkt = 2 * qt + 2;                      // block-uniform (barriers)
  const int myNkt = (q0w + 31) / 64 + 1;           // this wave's causal bound
  for (int kt = 0; kt < nkt; kt++) {
    const int kt0 = kt * 64;
#pragma unroll
    for (int j = 0; j < 4; j++) {
      g2l16(kp + (size_t)(kt0 + j * 16 + krow) * 128 + kcg * 8, lKdst + j * 2048);
      g2l16(vp + (size_t)(j * 32 + vd) * 2048 + kt0 + vsg * 8, lVdst + j * 2048);
    }
    __syncthreads();
    if (kt < myNkt) {
      // S = Q K^T (pre-scaled): 32 q-rows x 64 k-cols
      f32x4 sc[2][4] = {};
#pragma unroll
      for (int ct = 0; ct < 4; ct++) {
        const int nrow = ct * 16 + l16;
#pragma unroll
        for (int st = 0; st < 4; st++) {
          bf16x8 kf = *(const bf16x8*)(lK + ((size_t)nrow * 16 + ((st * 4 + quad) ^ l16)) * 8);
          sc[0][ct] = __builtin_amdgcn_mfma_f32_16x16x32_bf16(qf[0][st], kf, sc[0][ct], 0, 0, 0);
          sc[1][ct] = __builtin_amdgcn_mfma_f32_16x16x32_bf16(qf[1][st], kf, sc[1][ct], 0, 0, 0);
        }
      }
      // exp (no max-subtract), causal mask only on the wave's LAST tile
      // (structurally exact: last tile always straddles/touches the diagonal,
      //  second-to-last never does — verified for all 4 wave offsets)
      const bool needmask = (kt == myNkt - 1);
#pragma unroll
      for (int rg = 0; rg < 2; rg++)
#pragma unroll
        for (int ct = 0; ct < 4; ct++) {
          const int col = kt0 + ct * 16 + l16;
          const int rowb = q0w + rg * 16 + quad * 4;
#pragma unroll
          for (int r = 0; r < 4; r++) {
            float s = sc[rg][ct][r];
            if (needmask && col > rowb + r) s = -1e30f;
            float e = __expf(s);
            lsum[rg][r] += e;
            pw[(rg * 16 + quad * 4 + r) * 72 + ct * 16 + l16] = (__bf16)e;
          }
        }
      // P: C-layout -> LDS -> A-layout fragments
      bf16x8 pf[2][2];
#pragma unroll
      for (int rg = 0; rg < 2; rg++)
#pragma unroll
        for (int sb = 0; sb < 2; sb++)
          pf[rg][sb] = *(const bf16x8*)(pw + (rg * 16 + l16) * 72 + sb * 32 + quad * 8);
      // O += P @ V
#pragma unroll
      for (int dt = 0; dt < 8; dt++) {
#pragma unroll
        for (int sb = 0; sb < 2; sb++) {
          bf16x8 vf = *(const bf16x8*)(lV +
              ((size_t)(dt * 16 + l16) * 8 + ((sb * 4 + quad) ^ (l16 & 7))) * 8);
          o[0][dt] = __builtin_amdgcn_mfma_f32_16x16x32_bf16(pf[0][sb], vf, o[0][dt], 0, 0, 0);
          o[1][dt] = __builtin_amdgcn_mfma_f32_16x16x32_bf16(pf[1][sb], vf, o[1][dt], 0, 0, 0);
        }
      }
    }
    __syncthreads();
  }
  // reduce l across the 16 col-lanes (once per wave)
#pragma unroll
  for (int m = 1; m < 16; m <<= 1)
#pragma unroll
    for (int rg = 0; rg < 2; rg++)
#pragma unroll
      for (int r = 0; r < 4; r++)
        lsum[rg][r] += __shfl_xor(lsum[rg][r], m, 64);
  float inv[2][4];
#pragma unroll
  for (int rg = 0; rg < 2; rg++)
#pragma unroll
    for (int r = 0; r < 4; r++) inv[rg][r] = 1.0f / lsum[rg][r];
#pragma unroll
  for (int rg = 0; rg < 2; rg++)
#pragma unroll
    for (int dt = 0; dt < 8; dt++)
#pragma unroll
      for (int r = 0; r < 4; r++)
        ob[(size_t)(bi * 2048 + q0w + rg * 16 + quad * 4 + r) * 2048 + h * 128 + dt * 16 + l16] =
            f2bf(o[rg][dt][r] * inv[rg][r]);
}

extern "C" void kernel_launch(void* const* d_in, const int* in_sizes, int n_in,
                              void* d_out, int out_size, void* d_ws, size_t ws_size,
                              hipStream_t stream) {
  const float* x = (const float*)d_in[0];
  const float* wqkv = (const float*)d_in[1];
  const float* wout = (const float*)d_in[2];
  // d_in[3] = mask, unused (causal analytically)
  char* ws = (char*)d_ws;
  const size_t MiB = 1ull << 20;
  unsigned short* xb    = (unsigned short*)(ws + 0);         // [4096,2048] bf16   16 MiB
  unsigned short* wqkvT = (unsigned short*)(ws + 16 * MiB);  // [6144,2048] bf16   24 MiB
  unsigned short* woutT = (unsigned short*)(ws + 40 * MiB);  // [2048,2048] bf16    8 MiB
  unsigned short* qb    = (unsigned short*)(ws + 48 * MiB);  // [32,2048,128] bf16 16 MiB
  unsigned short* kb    = (unsigned short*)(ws + 64 * MiB);  // [32,2048,128]      16 MiB
  unsigned short* vb    = (unsigned short*)(ws + 80 * MiB);  // [32,2048,128]      16 MiB
  unsigned short* vtb   = (unsigned short*)(ws + 96 * MiB);  // [32,128,2048]      16 MiB
  unsigned short* attnb = (unsigned short*)(ws + 112 * MiB); // [4096,2048] bf16   16 MiB
  float* outF = (float*)d_out;

  cvt_f32_bf16_k<<<8192, 256, 0, stream>>>(x, xb);
  tr_cvt_k<<<dim3(96, 32), 256, 0, stream>>>(wqkv, wqkvT, 2048, 6144);
  tr_cvt_k<<<dim3(32, 32), 256, 0, stream>>>(wout, woutT, 2048, 2048);
  gemm_bt_k<0><<<dim3(48, 32), 256, 0, stream>>>(xb, wqkvT, 2048, 6144, nullptr, qb, kb, vb);
  rope_k<<<32768, 256, 0, stream>>>(qb, kb);
  tr_b16_k<<<dim3(2, 32, 32), 256, 0, stream>>>(vb, vtb, 2048, 128);
  attn_k<<<dim3(16, 32), 256, 0, stream>>>(qb, kb, vtb, attnb);
  gemm_bt_k<1><<<dim3(16, 32), 256, 0, stream>>>(attnb, woutT, 2048, 2048, outF,
                                                 nullptr, nullptr, nullptr);
}